// Round 7
// baseline (427.854 us; speedup 1.0000x reference)
//
#include <hip/hip_runtime.h>
#include <hip/hip_bf16.h>

typedef __bf16 bf16;
typedef __attribute__((ext_vector_type(8))) __bf16 bf16x8;
typedef __attribute__((ext_vector_type(4))) float f32x4;

#define MFMA16(a, b, c) __builtin_amdgcn_mfma_f32_16x16x32_bf16(a, b, c, 0, 0, 0)

#define LGKM_FENCE()                                      \
  do {                                                    \
    asm volatile("s_waitcnt lgkmcnt(0)" ::: "memory");    \
    __builtin_amdgcn_sched_barrier(0);                    \
  } while (0)

#define SCHED0() __builtin_amdgcn_sched_barrier(0)
#define SBAR() __builtin_amdgcn_s_barrier()
#define PRIO(x) __builtin_amdgcn_s_setprio(x)

typedef __attribute__((address_space(1))) void gvoid;
typedef __attribute__((address_space(3))) void lvoid;
__device__ __forceinline__ void gl16(const bf16* g, bf16* l) {
  __builtin_amdgcn_global_load_lds((gvoid*)g, (lvoid*)l, 16, 0, 0);
}

// Problem geometry: B=4, T=1024, D=1024, H=16, HD=64, DFF=4096, M=4096

// ---------------------------------------------------------------------------
struct WPtrs { const float* p[8]; };

__global__ __launch_bounds__(256) void wtrans8_k(WPtrs wp, bf16* __restrict__ dst) {
  const float* w = wp.p[blockIdx.z];
  bf16* wt = dst + (size_t)blockIdx.z * 1024 * 1024;
  __shared__ float t[32][33];
  const int tx = threadIdx.x & 31, ty = threadIdx.x >> 5;
  const int nb = blockIdx.x * 32, kb = blockIdx.y * 32;
  for (int i = 0; i < 4; ++i)
    t[ty + i * 8][tx] = w[(size_t)(kb + ty + i * 8) * 1024 + nb + tx];
  __syncthreads();
  for (int i = 0; i < 4; ++i)
    wt[(size_t)(nb + ty + i * 8) * 1024 + kb + tx] = (bf16)t[tx][ty + i * 8];
}

__global__ __launch_bounds__(256) void wtrans_k(const float* __restrict__ w,
                                                bf16* __restrict__ wt,
                                                int K, int N) {
  __shared__ float t[32][33];
  const int tx = threadIdx.x & 31, ty = threadIdx.x >> 5;
  const int nb = blockIdx.x * 32, kb = blockIdx.y * 32;
  for (int i = 0; i < 4; ++i)
    t[ty + i * 8][tx] = w[(size_t)(kb + ty + i * 8) * N + nb + tx];
  __syncthreads();
  for (int i = 0; i < 4; ++i)
    wt[(size_t)(nb + ty + i * 8) * K + kb + tx] = (bf16)t[tx][ty + i * 8];
}

// ---------------------------------------------------------------------------
__global__ __launch_bounds__(256) void tobf_k(const float* __restrict__ in,
                                              bf16* __restrict__ out) {
  const int i = blockIdx.x * 256 + threadIdx.x;
  const float4 v = ((const float4*)in)[i];
  bf16* o = out + (size_t)i * 4;
  o[0] = (bf16)v.x; o[1] = (bf16)v.y; o[2] = (bf16)v.z; o[3] = (bf16)v.w;
}

struct B5 { const float* s[5]; };
__global__ __launch_bounds__(256) void bpack_k(B5 bp, float* __restrict__ bq3,
                                               float* __restrict__ bkv2) {
  const int i = blockIdx.x;
  float* d = (i < 3) ? bq3 + i * 1024 : bkv2 + (i - 3) * 1024;
  ((float4*)d)[threadIdx.x] = ((const float4*)bp.s[i])[threadIdx.x];
}

// ---------------------------------------------------------------------------
__global__ __launch_bounds__(256) void ln_k(const float* __restrict__ x,
                                            const float* __restrict__ g,
                                            const float* __restrict__ bta,
                                            bf16* __restrict__ out) {
  const int row = blockIdx.x, tid = threadIdx.x;
  const float4 v = ((const float4*)(x + (size_t)row * 1024))[tid];
  float s = v.x + v.y + v.z + v.w;
  float sq = v.x * v.x + v.y * v.y + v.z * v.z + v.w * v.w;
  for (int d = 1; d < 64; d <<= 1) { s += __shfl_xor(s, d); sq += __shfl_xor(sq, d); }
  __shared__ float rs[4], rq[4];
  const int w = tid >> 6, lane = tid & 63;
  if (lane == 0) { rs[w] = s; rq[w] = sq; }
  __syncthreads();
  s = rs[0] + rs[1] + rs[2] + rs[3];
  sq = rq[0] + rq[1] + rq[2] + rq[3];
  const float mean = s * (1.0f / 1024.0f);
  const float var = sq * (1.0f / 1024.0f) - mean * mean;
  const float rstd = rsqrtf(var + 1e-5f);
  const float4 gv = ((const float4*)g)[tid];
  const float4 bv = ((const float4*)bta)[tid];
  bf16* o = out + (size_t)row * 1024 + tid * 4;
  o[0] = (bf16)((v.x - mean) * rstd * gv.x + bv.x);
  o[1] = (bf16)((v.y - mean) * rstd * gv.y + bv.y);
  o[2] = (bf16)((v.z - mean) * rstd * gv.z + bv.z);
  o[3] = (bf16)((v.w - mean) * rstd * gv.w + bv.w);
}

// ---------------------------------------------------------------------------
// GEMM 256x256, BK=64, 8 waves (2M x 4N, each 128x64 out), 8-phase schedule
// with counted vmcnt (m201 template). LDS 128KB dbuf, XOR-chunk swizzle.
// Per K-tile: P1{ldA-mh0+ldB-n0} P2{ldB-n1} P3{ldA-mh1, stage B(t+2)}
// P4{stage A(t+2)}; each phase: bar; lgkm0; prio1; 16 MFMA; prio0; bar.
// EPI: 3 bias+GELU->bf16 | 4 fused QKV | 5 fused KV
// ---------------------------------------------------------------------------
template <int EPI>
__global__ __launch_bounds__(512, 2) void gemm256_k(const bf16* __restrict__ A,
                                                    const bf16* __restrict__ Bt,
                                                    const float* __restrict__ bias,
                                                    void* __restrict__ o0,
                                                    void* __restrict__ o1,
                                                    void* __restrict__ o2,
                                                    int K, int N) {
  __shared__ bf16 As[2][2][128 * 64];  // [buf][row-half][...]
  __shared__ bf16 Bs[2][2][128 * 64];
  const int tid = threadIdx.x;
  const int lane = tid & 63, w = tid >> 6;
  const int wr = w >> 2, wc = w & 3;  // 2 x 4 wave grid
  const int l15 = lane & 15, l4 = lane >> 4;
  const int gx = gridDim.x;
  const int nwg = gx * gridDim.y;
  const int flat = blockIdx.x + blockIdx.y * gx;
  const int swz = (flat & 7) * (nwg >> 3) + (flat >> 3);
  const size_t bm = swz / gx, bn = swz % gx;
  const bf16* Ab = A + bm * 256 * (size_t)K;
  const bf16* Bb = Bt + bn * 256 * (size_t)K;

  const f32x4 zero4 = {0.f, 0.f, 0.f, 0.f};
  f32x4 acc[8][4];
  for (int m = 0; m < 8; ++m)
    for (int n = 0; n < 4; ++n) acc[m][n] = zero4;

  // Staging: 1024 16B-slots per 128x64 half-tile; thread t covers slots
  // t and t+512. slot row = s>>3, lds chunk = s&7, global chunk ^= row&7.
  const int srow = tid >> 3;                      // 0..63
  const int gck = ((tid & 7) ^ (srow & 7)) * 8;   // elems
  auto stA = [&](int buf, int half, int t) {
    const bf16* src = Ab + (size_t)(half * 128 + srow) * K + t * 64 + gck;
    bf16* dst = &As[buf][half][tid * 8];
    gl16(src, dst);
    gl16(src + (size_t)64 * K, dst + 4096);
  };
  auto stB = [&](int buf, int half, int t) {
    const bf16* src = Bb + (size_t)(half * 128 + srow) * K + t * 64 + gck;
    bf16* dst = &Bs[buf][half][tid * 8];
    gl16(src, dst);
    gl16(src + (size_t)64 * K, dst + 4096);
  };

  // Fragment reads (swizzled): row r in half, K-half kh chunk = (kh*4+l4)^(r&7)
  const int xr = l15 & 7;
  const int ca0 = (l4 ^ xr) * 8, ca1 = ((4 + l4) ^ xr) * 8;
  bf16x8 af[4][2];        // current m-half A frags
  bf16x8 bfr[2][2][2];    // [n-half][j][kh] B frags, whole K-tile
  const int brow0 = (wc & 1) * 64;  // B row base within half wc>>1
  auto ldA = [&](int buf, int mh) {
#pragma unroll
    for (int i = 0; i < 4; ++i) {
      const int r = mh * 64 + i * 16 + l15;
      af[i][0] = *(const bf16x8*)&As[buf][wr][r * 64 + ca0];
      af[i][1] = *(const bf16x8*)&As[buf][wr][r * 64 + ca1];
    }
  };
  auto ldB = [&](int buf, int nh) {
#pragma unroll
    for (int j = 0; j < 2; ++j) {
      const int r = brow0 + (nh * 2 + j) * 16 + l15;
      bfr[nh][j][0] = *(const bf16x8*)&Bs[buf][wc >> 1][r * 64 + ca0];
      bfr[nh][j][1] = *(const bf16x8*)&Bs[buf][wc >> 1][r * 64 + ca1];
    }
  };
  auto mfma16 = [&](int mh, int nh) {
#pragma unroll
    for (int i = 0; i < 4; ++i)
#pragma unroll
      for (int j = 0; j < 2; ++j) {
        acc[mh * 4 + i][nh * 2 + j] =
            MFMA16(af[i][0], bfr[nh][j][0], acc[mh * 4 + i][nh * 2 + j]);
        acc[mh * 4 + i][nh * 2 + j] =
            MFMA16(af[i][1], bfr[nh][j][1], acc[mh * 4 + i][nh * 2 + j]);
      }
  };

  auto ktile = [&](int buf, int tstage, bool dostage) {
    // P1
    ldA(buf, 0); ldB(buf, 0); SCHED0();
    SBAR();
    LGKM_FENCE();
    PRIO(1); mfma16(0, 0); PRIO(0); SCHED0();
    SBAR();
    // P2
    ldB(buf, 1); SCHED0();
    SBAR();
    LGKM_FENCE();
    PRIO(1); mfma16(0, 1); PRIO(0); SCHED0();
    SBAR();
    // P3  (B-regions of buf fully read by P2-end -> stage B of tile t+2)
    ldA(buf, 1);
    if (dostage) { stB(buf, 0, tstage); stB(buf, 1, tstage); }
    SCHED0();
    SBAR();
    LGKM_FENCE();
    PRIO(1); mfma16(1, 0); PRIO(0); SCHED0();
    SBAR();
    // P4  (A-regions fully read by P3-end -> stage A of tile t+2)
    if (dostage) { stA(buf, 0, tstage); stA(buf, 1, tstage); }
    SCHED0();
    SBAR();
    PRIO(1); mfma16(1, 1); PRIO(0); SCHED0();
    SBAR();
  };

  const int nt = K >> 6;  // >= 16 for all our shapes
  stA(0, 0, 0); stA(0, 1, 0); stB(0, 0, 0); stB(0, 1, 0);
  stA(1, 0, 1); stA(1, 1, 1); stB(1, 0, 1); stB(1, 1, 1);
  for (int t = 0; t < nt; ++t) {
    const int buf = t & 1;
    if (t < nt - 1) {
      asm volatile("s_waitcnt vmcnt(8)" ::: "memory");
    } else {
      asm volatile("s_waitcnt vmcnt(0)" ::: "memory");
    }
    SBAR(); SCHED0();  // all waves' loads for this buf landed
    ktile(buf, t + 2, t < nt - 2);
  }

  for (int m = 0; m < 8; ++m) {
    const int row0 = (int)bm * 256 + wr * 128 + m * 16 + l4 * 4;
    for (int n = 0; n < 4; ++n) {
      const int col = (int)bn * 256 + wc * 64 + n * 16 + l15;
      const float bv = bias[col];
      for (int r = 0; r < 4; ++r) {
        const int row = row0 + r;
        const float v = acc[m][n][r] + bv;
        if constexpr (EPI == 3) {
          const float gl = 0.5f * v * (1.0f + erff(v * 0.70710678118f));
          ((bf16*)o0)[(size_t)row * N + col] = (bf16)gl;
        } else {
          const int which = col >> 10, c = col & 1023;
          const int nplain = (EPI == 4) ? 2 : 1;
          if (which < nplain) {
            bf16* op = (bf16*)(which == 0 ? o0 : o1);
            op[(size_t)row * 1024 + c] = (bf16)v;
          } else {
            bf16* op = (bf16*)((EPI == 4) ? o2 : o1);
            const int b = row >> 10, t = row & 1023;
            const int h = c >> 6, hd = c & 63;
            op[(size_t)((b * 16 + h) * 64 + hd) * 1024 + t] = (bf16)v;
          }
        }
      }
    }
  }
}

// ---------------------------------------------------------------------------
// GEMM 128x64, BK=64, depth-2 counted-vmcnt pipeline (for N=1024 outputs).
// EPI: 0 bias->bf16 | 2 bias+res->fp32
// ---------------------------------------------------------------------------
template <int EPI>
__global__ __launch_bounds__(256) void gemm64_k(const bf16* __restrict__ A,
                                                const bf16* __restrict__ Bt,
                                                const float* __restrict__ bias,
                                                const float* __restrict__ res,
                                                void* __restrict__ o0,
                                                int K, int N) {
  __shared__ bf16 As[2][128 * 64];
  __shared__ bf16 Bs[2][64 * 64];
  const int tid = threadIdx.x;
  const int lane = tid & 63, w = tid >> 6;
  const int l15 = lane & 15, l4 = lane >> 4;
  const int gx = gridDim.x;
  const int nwg = gx * gridDim.y;
  const int flat = blockIdx.x + blockIdx.y * gx;
  const int swz = (flat & 7) * (nwg >> 3) + (flat >> 3);
  const size_t bm = swz / gx, bn = swz % gx;
  const bf16* Ab = A + bm * 128 * (size_t)K;
  const bf16* Bb = Bt + bn * 64 * (size_t)K;

  const f32x4 zero4 = {0.f, 0.f, 0.f, 0.f};
  f32x4 acc[2][4];
  for (int m = 0; m < 2; ++m)
    for (int n = 0; n < 4; ++n) acc[m][n] = zero4;

  const int srow = lane >> 3;
  const int gck = ((lane & 7) ^ srow) * 8;
  auto stage = [&](int buf, int t) {
    const int kt = t * 64;
    for (int j = 0; j < 4; ++j) {
      const int row = w * 32 + j * 8 + srow;
      gl16(Ab + (size_t)row * K + kt + gck, As[buf] + (w * 256 + j * 64 + lane) * 8);
    }
    for (int j = 0; j < 2; ++j) {
      const int row = w * 16 + j * 8 + srow;
      gl16(Bb + (size_t)row * K + kt + gck, Bs[buf] + (w * 128 + j * 64 + lane) * 8);
    }
  };
  const int xr = l15 & 7;
  const int c0 = (l4 ^ xr) * 8, c1 = ((4 + l4) ^ xr) * 8;
  auto compute = [&](int buf) {
    bf16x8 af[2][2], bfr[4][2];
    for (int m = 0; m < 2; ++m) {
      const int ro = (w * 32 + m * 16 + l15) * 64;
      af[m][0] = *(const bf16x8*)&As[buf][ro + c0];
      af[m][1] = *(const bf16x8*)&As[buf][ro + c1];
    }
    for (int n = 0; n < 4; ++n) {
      const int ro = (n * 16 + l15) * 64;
      bfr[n][0] = *(const bf16x8*)&Bs[buf][ro + c0];
      bfr[n][1] = *(const bf16x8*)&Bs[buf][ro + c1];
    }
    PRIO(1);
    for (int m = 0; m < 2; ++m)
      for (int n = 0; n < 4; ++n) {
        acc[m][n] = MFMA16(af[m][0], bfr[n][0], acc[m][n]);
        acc[m][n] = MFMA16(af[m][1], bfr[n][1], acc[m][n]);
      }
    PRIO(0);
  };

  const int nt = K >> 6;
  stage(0, 0);
  stage(1, 1);
  int cur = 0;
  for (int t = 0; t < nt - 2; ++t) {
    asm volatile("s_waitcnt vmcnt(6)" ::: "memory");
    SBAR(); SCHED0();
    compute(cur);
    SCHED0(); SBAR(); SCHED0();
    stage(cur, t + 2);
    cur ^= 1;
  }
  asm volatile("s_waitcnt vmcnt(6)" ::: "memory");
  SBAR(); SCHED0();
  compute(cur);
  cur ^= 1;
  asm volatile("s_waitcnt vmcnt(0)" ::: "memory");
  SBAR(); SCHED0();
  compute(cur);

  for (int m = 0; m < 2; ++m) {
    const int row0 = (int)bm * 128 + w * 32 + m * 16 + l4 * 4;
    for (int n = 0; n < 4; ++n) {
      const int col = (int)bn * 64 + n * 16 + l15;
      const float bv = bias[col];
      for (int r = 0; r < 4; ++r) {
        const int row = row0 + r;
        const float v = acc[m][n][r] + bv;
        if constexpr (EPI == 0) {
          ((bf16*)o0)[(size_t)row * N + col] = (bf16)v;
        } else {
          ((float*)o0)[(size_t)row * N + col] = v + res[(size_t)row * N + col];
        }
      }
    }
  }
}

// ---------------------------------------------------------------------------
// Causal flash attention with cooperative LDS K/V staging (unchanged).
// ---------------------------------------------------------------------------
__global__ __launch_bounds__(512) void attn_k(const bf16* __restrict__ Q,
                                              const bf16* __restrict__ Kb,
                                              const bf16* __restrict__ Vt,
                                              bf16* __restrict__ O) {
  __shared__ bf16 Ks[2][64 * 64];
  __shared__ bf16 Vs[2][64 * 64];
  __shared__ bf16 Plds[8][16][72];
  const int bx = blockIdx.x, bh = blockIdx.y;
  const int b = bh >> 4, h = bh & 15;
  const int tid = threadIdx.x, lane = tid & 63, w = tid >> 6;
  const int myqt = (w < 4) ? bx : (15 - bx);
  const int qbase = myqt * 64 + (w & 3) * 16;
  const int l15 = lane & 15, l4 = lane >> 4;
  const int nt = 16 - bx;

  const bf16* Qp = Q + (size_t)(b * 1024 + qbase + l15) * 1024 + h * 64 + l4 * 8;
  bf16x8 qf0 = *(const bf16x8*)Qp;
  bf16x8 qf1 = *(const bf16x8*)(Qp + 32);
  for (int i = 0; i < 8; ++i) {
    qf0[i] = (bf16)((float)qf0[i] * 0.125f);
    qf1[i] = (bf16)((float)qf1[i] * 0.125f);
  }
  bf16x8 onesf;
  for (int i = 0; i < 8; ++i) onesf[i] = (bf16)1.0f;

  const f32x4 zero4 = {0.f, 0.f, 0.f, 0.f};
  f32x4 o[4], ol;
  float mrow[4];
  for (int d = 0; d < 4; ++d) o[d] = zero4;
  ol = zero4;
  for (int r = 0; r < 4; ++r) mrow[r] = -1e30f;

  const int qrow0 = qbase + l4 * 4;

  const int srow = tid >> 3;
  const int cg = (tid & 7) ^ (srow & 7);
  const bf16* Kg = Kb + (size_t)(b * 1024 + srow) * 1024 + h * 64 + cg * 8;
  const bf16* Vg = Vt + (size_t)(bh * 64 + srow) * 1024 + cg * 8;
  auto stage = [&](int buf, int t) {
    gl16(Kg + (size_t)t * 64 * 1024, Ks[buf] + tid * 8);
    gl16(Vg + t * 64, Vs[buf] + tid * 8);
  };

  const int xr = l15 & 7;
  const int fc0 = (l4 ^ xr) * 8, fc1 = ((4 + l4) ^ xr) * 8;

  auto compute = [&](int buf, int kt) {
    const int kbase = kt * 64;
    f32x4 s[4];
    for (int n = 0; n < 4; ++n) s[n] = zero4;
    PRIO(1);
    for (int n = 0; n < 4; ++n) {
      const int ro = (n * 16 + l15) * 64;
      const bf16x8 kf0 = *(const bf16x8*)&Ks[buf][ro + fc0];
      const bf16x8 kf1 = *(const bf16x8*)&Ks[buf][ro + fc1];
      s[n] = MFMA16(qf0, kf0, s[n]);
      s[n] = MFMA16(qf1, kf1, s[n]);
    }
    PRIO(0);
    if (kt == myqt) {
      for (int n = 0; n < 4; ++n) {
        const int kc = kbase + n * 16 + l15;
        for (int r = 0; r < 4; ++r)
          if (kc > qrow0 + r) s[n][r] = -1e30f;
      }
    }
    float mx[4];
    for (int r = 0; r < 4; ++r)
      mx[r] = fmaxf(fmaxf(s[0][r], s[1][r]), fmaxf(s[2][r], s[3][r]));
    for (int d0 = 1; d0 < 16; d0 <<= 1)
      for (int r = 0; r < 4; ++r) mx[r] = fmaxf(mx[r], __shfl_xor(mx[r], d0));
    float alpha[4];
    for (int r = 0; r < 4; ++r) {
      const float mnew = fmaxf(mrow[r], mx[r]);
      alpha[r] = __expf(mrow[r] - mnew);
      mrow[r] = mnew;
    }
    for (int n = 0; n < 4; ++n)
      for (int r = 0; r < 4; ++r) s[n][r] = __expf(s[n][r] - mrow[r]);
    for (int d = 0; d < 4; ++d)
      for (int r = 0; r < 4; ++r) o[d][r] *= alpha[r];
    for (int r = 0; r < 4; ++r) ol[r] *= alpha[r];

    LGKM_FENCE();
    for (int r = 0; r < 4; ++r)
      for (int n = 0; n < 4; ++n)
        Plds[w][l4 * 4 + r][n * 16 + l15] = (bf16)s[n][r];
    LGKM_FENCE();
    const bf16x8 pf0 = *(const bf16x8*)&Plds[w][l15][l4 * 8];
    const bf16x8 pf1 = *(const bf16x8*)&Plds[w][l15][32 + l4 * 8];

    PRIO(1);
    for (int d = 0; d < 4; ++d) {
      const int ro = (d * 16 + l15) * 64;
      const bf16x8 vf0 = *(const bf16x8*)&Vs[buf][ro + fc0];
      const bf16x8 vf1 = *(const bf16x8*)&Vs[buf][ro + fc1];
      o[d] = MFMA16(pf0, vf0, o[d]);
      o[d] = MFMA16(pf1, vf1, o[d]);
    }
    ol = MFMA16(pf0, onesf, ol);
    ol = MFMA16(pf1, onesf, ol);
    PRIO(0);
  };

  stage(0, 0);
  stage(1, 1);
  int cur = 0;
  for (int t = 0; t < nt - 2; ++t) {
    asm volatile("s_waitcnt vmcnt(2)" ::: "memory");
    SBAR(); SCHED0();
    if (t <= myqt) compute(cur, t);
    SCHED0(); SBAR(); SCHED0();
    stage(cur, t + 2);
    cur ^= 1;
  }
  asm volatile("s_waitcnt vmcnt(2)" ::: "memory");
  SBAR(); SCHED0();
  if (nt - 2 <= myqt) compute(cur, nt - 2);
  cur ^= 1;
  asm volatile("s_waitcnt vmcnt(0)" ::: "memory");
  SBAR(); SCHED0();
  if (nt - 1 <= myqt) compute(cur, nt - 1);

  for (int r = 0; r < 4; ++r) {
    const float inv = 1.0f / ol[r];
    for (int d = 0; d < 4; ++d) {
      O[(size_t)(b * 1024 + qbase + l4 * 4 + r) * 1024 + h * 64 + d * 16 + l15] =
          (bf16)(o[d][r] * inv);
    }
  }
}

// ---------------------------------------------------------------------------
extern "C" void kernel_launch(void* const* d_in, const int* in_sizes, int n_in,
                              void* d_out, int out_size, void* d_ws, size_t ws_size,
                              hipStream_t stream) {
  const float* x_enc = (const float*)d_in[0];
  const float* x     = (const float*)d_in[1];
  const float* ln1_g = (const float*)d_in[2];
  const float* ln1_b = (const float*)d_in[3];
  const float* ln2_g = (const float*)d_in[4];
  const float* ln2_b = (const float*)d_in[5];
  const float* sa_wq = (const float*)d_in[6];  const float* sa_bq = (const float*)d_in[7];
  const float* sa_wk = (const float*)d_in[8];  const float* sa_bk = (const float*)d_in[9];
  const float* sa_wv = (const float*)d_in[10]; const float* sa_bv = (const float*)d_in[11];
  const float* sa_wo = (const float*)d_in[12]; const float* sa_bo = (const float*)d_in[13];
  const float* ca_wq = (const float*)d_in[14]; const float* ca_bq = (const float*)d_in[15];
  const float* ca_wk = (const float*)d_in[16]; const float* ca_bk = (const float*)d_in[17];
  const float* ca_wv = (const float*)d_in[18]; const float* ca_bv = (const float*)d_in[19];
  const float* ca_wo = (const float*)d_in[20]; const float* ca_bo = (const float*)d_in[21];
  const float* mlp_w1 = (const float*)d_in[22]; const float* mlp_b1 = (const float*)d_in[23];
  const float* mlp_w2 = (const float*)d_in[24]; const float* mlp_b2 = (const float*)d_in[25];

  char* ws = (char*)d_ws;
  size_t off = 0;
  auto take = [&](size_t bytes) { char* p = ws + off; off += (bytes + 255) & ~(size_t)255; return p; };

  bf16* wt8 = (bf16*)take((size_t)8 * 1024 * 1024 * 2);
  bf16* w1t   = (bf16*)take((size_t)4096 * 1024 * 2);
  bf16* w2t   = (bf16*)take((size_t)1024 * 4096 * 2);
  bf16* lnbuf = (bf16*)take((size_t)4096 * 1024 * 2);
  bf16* xe_bf = (bf16*)take((size_t)4096 * 1024 * 2);
  bf16* Qb    = (bf16*)take((size_t)4096 * 1024 * 2);
  bf16* Kbf   = (bf16*)take((size_t)4096 * 1024 * 2);
  bf16* Vtb   = (bf16*)take((size_t)4096 * 1024 * 2);
  bf16* AOb   = (bf16*)take((size_t)4096 * 1024 * 2);
  float* x1   = (float*)take((size_t)4096 * 1024 * 4);
  float* x2   = (float*)take((size_t)4096 * 1024 * 4);
  bf16* Hb    = (bf16*)take((size_t)4096 * 4096 * 2);
  float* bq3  = (float*)take((size_t)3072 * 4);
  float* bkv2 = (float*)take((size_t)2048 * 4);

  bf16* wt[8];
  for (int i = 0; i < 8; ++i) wt[i] = wt8 + (size_t)i * 1024 * 1024;

  const dim3 blk(256);
  WPtrs wp = {{sa_wq, sa_wk, sa_wv, sa_wo, ca_wq, ca_wk, ca_wv, ca_wo}};
  wtrans8_k<<<dim3(32, 32, 8), blk, 0, stream>>>(wp, wt8);
  wtrans_k<<<dim3(128, 32), blk, 0, stream>>>(mlp_w1, w1t, 1024, 4096);
  wtrans_k<<<dim3(32, 128), blk, 0, stream>>>(mlp_w2, w2t, 4096, 1024);
  tobf_k<<<4096, blk, 0, stream>>>(x_enc, xe_bf);
  B5 bp = {{sa_bq, sa_bk, sa_bv, ca_bk, ca_bv}};
  bpack_k<<<5, blk, 0, stream>>>(bp, bq3, bkv2);

  // x = x + SelfAttn(ln1(x)) — fused QKV projection (N=3072, 256^2 8-phase)
  ln_k<<<4096, blk, 0, stream>>>(x, ln1_g, ln1_b, lnbuf);
  gemm256_k<4><<<dim3(12, 16), dim3(512), 0, stream>>>(lnbuf, wt[0], bq3,
                                                       Qb, Kbf, Vtb, 1024, 3072);
  attn_k<<<dim3(8, 64), dim3(512), 0, stream>>>(Qb, Kbf, Vtb, AOb);
  gemm64_k<2><<<dim3(16, 32), blk, 0, stream>>>(AOb, wt[3], sa_bo, x, x1, 1024, 1024);

  // x = x + CrossAttn(ln1(x), x_encoder) — fused KV (N=2048, 256^2 8-phase)
  ln_k<<<4096, blk, 0, stream>>>(x1, ln1_g, ln1_b, lnbuf);
  gemm64_k<0><<<dim3(16, 32), blk, 0, stream>>>(lnbuf, wt[4], ca_bq, nullptr, Qb, 1024, 1024);
  gemm256_k<5><<<dim3(8, 16), dim3(512), 0, stream>>>(xe_bf, wt[5], bkv2,
                                                      Kbf, Vtb, nullptr, 1024, 2048);
  attn_k<<<dim3(8, 64), dim3(512), 0, stream>>>(Qb, Kbf, Vtb, AOb);
  gemm64_k<2><<<dim3(16, 32), blk, 0, stream>>>(AOb, wt[7], ca_bo, x1, x2, 1024, 1024);

  // x = x + MLP(ln2(x))
  ln_k<<<4096, blk, 0, stream>>>(x2, ln2_g, ln2_b, lnbuf);
  gemm256_k<3><<<dim3(16, 16), dim3(512), 0, stream>>>(lnbuf, w1t, mlp_b1,
                                                       Hb, nullptr, nullptr, 1024, 4096);
  gemm64_k<2><<<dim3(16, 32), blk, 0, stream>>>(Hb, w2t, mlp_b2, x2,
                                                (float*)d_out, 4096, 1024);

  (void)in_sizes; (void)n_in; (void)out_size; (void)ws_size;
}

// Round 8
// 381.951 us; speedup vs baseline: 1.1202x; 1.1202x over previous
//
#include <hip/hip_runtime.h>
#include <hip/hip_bf16.h>

typedef __bf16 bf16;
typedef __attribute__((ext_vector_type(8))) __bf16 bf16x8;
typedef __attribute__((ext_vector_type(4))) float f32x4;

#define MFMA16(a, b, c) __builtin_amdgcn_mfma_f32_16x16x32_bf16(a, b, c, 0, 0, 0)

#define LGKM_FENCE()                                      \
  do {                                                    \
    asm volatile("s_waitcnt lgkmcnt(0)" ::: "memory");    \
    __builtin_amdgcn_sched_barrier(0);                    \
  } while (0)

#define SCHED0() __builtin_amdgcn_sched_barrier(0)
#define SBAR() __builtin_amdgcn_s_barrier()
#define PRIO(x) __builtin_amdgcn_s_setprio(x)

typedef __attribute__((address_space(1))) void gvoid;
typedef __attribute__((address_space(3))) void lvoid;
__device__ __forceinline__ void gl16(const bf16* g, bf16* l) {
  __builtin_amdgcn_global_load_lds((gvoid*)g, (lvoid*)l, 16, 0, 0);
}

// Problem geometry: B=4, T=1024, D=1024, H=16, HD=64, DFF=4096, M=4096

// ---------------------------------------------------------------------------
struct WPtrs { const float* p[8]; };

__global__ __launch_bounds__(256) void wtrans8_k(WPtrs wp, bf16* __restrict__ dst) {
  const float* w = wp.p[blockIdx.z];
  bf16* wt = dst + (size_t)blockIdx.z * 1024 * 1024;
  __shared__ float t[32][33];
  const int tx = threadIdx.x & 31, ty = threadIdx.x >> 5;
  const int nb = blockIdx.x * 32, kb = blockIdx.y * 32;
  for (int i = 0; i < 4; ++i)
    t[ty + i * 8][tx] = w[(size_t)(kb + ty + i * 8) * 1024 + nb + tx];
  __syncthreads();
  for (int i = 0; i < 4; ++i)
    wt[(size_t)(nb + ty + i * 8) * 1024 + kb + tx] = (bf16)t[tx][ty + i * 8];
}

__global__ __launch_bounds__(256) void wtrans_k(const float* __restrict__ w,
                                                bf16* __restrict__ wt,
                                                int K, int N) {
  __shared__ float t[32][33];
  const int tx = threadIdx.x & 31, ty = threadIdx.x >> 5;
  const int nb = blockIdx.x * 32, kb = blockIdx.y * 32;
  for (int i = 0; i < 4; ++i)
    t[ty + i * 8][tx] = w[(size_t)(kb + ty + i * 8) * N + nb + tx];
  __syncthreads();
  for (int i = 0; i < 4; ++i)
    wt[(size_t)(nb + ty + i * 8) * K + kb + tx] = (bf16)t[tx][ty + i * 8];
}

// ---------------------------------------------------------------------------
__global__ __launch_bounds__(256) void tobf_k(const float* __restrict__ in,
                                              bf16* __restrict__ out) {
  const int i = blockIdx.x * 256 + threadIdx.x;
  const float4 v = ((const float4*)in)[i];
  bf16* o = out + (size_t)i * 4;
  o[0] = (bf16)v.x; o[1] = (bf16)v.y; o[2] = (bf16)v.z; o[3] = (bf16)v.w;
}

struct B5 { const float* s[5]; };
__global__ __launch_bounds__(256) void bpack_k(B5 bp, float* __restrict__ bq3,
                                               float* __restrict__ bkv2) {
  const int i = blockIdx.x;
  float* d = (i < 3) ? bq3 + i * 1024 : bkv2 + (i - 3) * 1024;
  ((float4*)d)[threadIdx.x] = ((const float4*)bp.s[i])[threadIdx.x];
}

// ---------------------------------------------------------------------------
// V transpose: Vp[M=4096][1024] (head h in cols h*64..+63) ->
// Vt[B*H][HD=64][T=1024]. 64x64 LDS tiles, coalesced 16B on both sides.
// Grid (16 t-tiles, 64 bh), 512 threads.
// ---------------------------------------------------------------------------
__global__ __launch_bounds__(512) void vtrans_k(const bf16* __restrict__ Vp,
                                                bf16* __restrict__ Vt) {
  __shared__ bf16 tl[64][72];  // 144B row stride keeps 16B alignment
  const int tt = blockIdx.x, bh = blockIdx.y;
  const int b = bh >> 4, h = bh & 15;
  const int tid = threadIdx.x;
  const int row = tid >> 3, ck = tid & 7;  // row = t-in-tile, ck = hd chunk
  *(bf16x8*)&tl[row][ck * 8] =
      *(const bf16x8*)&Vp[(size_t)(b * 1024 + tt * 64 + row) * 1024 + h * 64 + ck * 8];
  __syncthreads();
  const int hd = tid >> 3, tc = tid & 7;   // hd row out, tc = t chunk
  bf16 tmp[8];
#pragma unroll
  for (int e = 0; e < 8; ++e) tmp[e] = tl[tc * 8 + e][hd];
  *(bf16x8*)&Vt[(size_t)(bh * 64 + hd) * 1024 + tt * 64 + tc * 8] = *(bf16x8*)tmp;
}

// ---------------------------------------------------------------------------
__global__ __launch_bounds__(256) void ln_k(const float* __restrict__ x,
                                            const float* __restrict__ g,
                                            const float* __restrict__ bta,
                                            bf16* __restrict__ out) {
  const int row = blockIdx.x, tid = threadIdx.x;
  const float4 v = ((const float4*)(x + (size_t)row * 1024))[tid];
  float s = v.x + v.y + v.z + v.w;
  float sq = v.x * v.x + v.y * v.y + v.z * v.z + v.w * v.w;
  for (int d = 1; d < 64; d <<= 1) { s += __shfl_xor(s, d); sq += __shfl_xor(sq, d); }
  __shared__ float rs[4], rq[4];
  const int w = tid >> 6, lane = tid & 63;
  if (lane == 0) { rs[w] = s; rq[w] = sq; }
  __syncthreads();
  s = rs[0] + rs[1] + rs[2] + rs[3];
  sq = rq[0] + rq[1] + rq[2] + rq[3];
  const float mean = s * (1.0f / 1024.0f);
  const float var = sq * (1.0f / 1024.0f) - mean * mean;
  const float rstd = rsqrtf(var + 1e-5f);
  const float4 gv = ((const float4*)g)[tid];
  const float4 bv = ((const float4*)bta)[tid];
  bf16* o = out + (size_t)row * 1024 + tid * 4;
  o[0] = (bf16)((v.x - mean) * rstd * gv.x + bv.x);
  o[1] = (bf16)((v.y - mean) * rstd * gv.y + bv.y);
  o[2] = (bf16)((v.z - mean) * rstd * gv.z + bv.z);
  o[3] = (bf16)((v.w - mean) * rstd * gv.w + bv.w);
}

// ---------------------------------------------------------------------------
// GEMM 128x128, BK=64, 4 waves, depth-2 counted-vmcnt pipeline, XOR-swizzled
// LDS. EPI: 0 bias->bf16 | 2 bias+res->fp32 | 3 bias+GELU->bf16
//      4 fused QKV (Q,K,V all plain bf16[M,1024]) | 5 fused KV (plain)
// ---------------------------------------------------------------------------
template <int EPI>
__global__ __launch_bounds__(256) void gemm_k(const bf16* __restrict__ A,
                                              const bf16* __restrict__ Bt,
                                              const float* __restrict__ bias,
                                              const float* __restrict__ res,
                                              void* __restrict__ o0,
                                              void* __restrict__ o1,
                                              void* __restrict__ o2,
                                              int K, int N) {
  __shared__ bf16 As[2][128 * 64];
  __shared__ bf16 Bs[2][128 * 64];
  const int tid = threadIdx.x;
  const int lane = tid & 63, w = tid >> 6;
  const int wr = w >> 1, wc = w & 1;
  const int l15 = lane & 15, l4 = lane >> 4;
  const int gx = gridDim.x;
  const int nwg = gx * gridDim.y;
  const int flat = blockIdx.x + blockIdx.y * gx;
  const int swz = (flat & 7) * (nwg >> 3) + (flat >> 3);
  const size_t bm = swz / gx, bn = swz % gx;
  const bf16* Ab = A + bm * 128 * (size_t)K;
  const bf16* Bb = Bt + bn * 128 * (size_t)K;

  const f32x4 zero4 = {0.f, 0.f, 0.f, 0.f};
  f32x4 acc[4][4];
  for (int m = 0; m < 4; ++m)
    for (int n = 0; n < 4; ++n) acc[m][n] = zero4;

  const int srow = lane >> 3;
  const int gck = ((lane & 7) ^ srow) * 8;
  auto stage = [&](int buf, int t) {
    const int kt = t * 64;
    for (int j = 0; j < 4; ++j) {
      const int row = w * 32 + j * 8 + srow;
      bf16* la = As[buf] + (w * 256 + j * 64 + lane) * 8;
      bf16* lb = Bs[buf] + (w * 256 + j * 64 + lane) * 8;
      gl16(Ab + (size_t)row * K + kt + gck, la);
      gl16(Bb + (size_t)row * K + kt + gck, lb);
    }
  };
  const int xr = l15 & 7;
  const int c0 = (l4 ^ xr) * 8, c1 = ((4 + l4) ^ xr) * 8;
  auto compute = [&](int buf) {
    bf16x8 af[4][2], bfr[4][2];
    for (int m = 0; m < 4; ++m) {
      const int ro = (wr * 64 + m * 16 + l15) * 64;
      af[m][0] = *(const bf16x8*)&As[buf][ro + c0];
      af[m][1] = *(const bf16x8*)&As[buf][ro + c1];
    }
    for (int n = 0; n < 4; ++n) {
      const int ro = (wc * 64 + n * 16 + l15) * 64;
      bfr[n][0] = *(const bf16x8*)&Bs[buf][ro + c0];
      bfr[n][1] = *(const bf16x8*)&Bs[buf][ro + c1];
    }
    PRIO(1);
    for (int m = 0; m < 4; ++m)
      for (int n = 0; n < 4; ++n) {
        acc[m][n] = MFMA16(af[m][0], bfr[n][0], acc[m][n]);
        acc[m][n] = MFMA16(af[m][1], bfr[n][1], acc[m][n]);
      }
    PRIO(0);
  };

  const int nt = K >> 6;
  stage(0, 0);
  stage(1, 1);
  int cur = 0;
  for (int t = 0; t < nt - 2; ++t) {
    asm volatile("s_waitcnt vmcnt(8)" ::: "memory");
    SBAR(); SCHED0();
    compute(cur);
    SCHED0(); SBAR(); SCHED0();
    stage(cur, t + 2);
    cur ^= 1;
  }
  asm volatile("s_waitcnt vmcnt(8)" ::: "memory");
  SBAR(); SCHED0();
  compute(cur);
  cur ^= 1;
  asm volatile("s_waitcnt vmcnt(0)" ::: "memory");
  SBAR(); SCHED0();
  compute(cur);

  for (int m = 0; m < 4; ++m) {
    const int row0 = (int)bm * 128 + wr * 64 + m * 16 + l4 * 4;
    for (int n = 0; n < 4; ++n) {
      const int col = (int)bn * 128 + wc * 64 + n * 16 + l15;
      const float bv = bias[col];
      for (int r = 0; r < 4; ++r) {
        const int row = row0 + r;
        const float v = acc[m][n][r] + bv;
        if constexpr (EPI == 0) {
          ((bf16*)o0)[(size_t)row * N + col] = (bf16)v;
        } else if constexpr (EPI == 2) {
          ((float*)o0)[(size_t)row * N + col] = v + res[(size_t)row * N + col];
        } else if constexpr (EPI == 3) {
          const float gl = 0.5f * v * (1.0f + erff(v * 0.70710678118f));
          ((bf16*)o0)[(size_t)row * N + col] = (bf16)gl;
        } else {
          const int which = col >> 10, c = col & 1023;
          bf16* op = (bf16*)(which == 0 ? o0 : (which == 1 ? o1 : o2));
          op[(size_t)row * 1024 + c] = (bf16)v;
        }
      }
    }
  }
}

// ---------------------------------------------------------------------------
// GEMM 256x256, BK=64, 8 waves, 8-phase counted-vmcnt schedule (MLP1 only,
// EPI=3). Isolated diagnostic of the 8-phase K-loop with clean plain writes.
// ---------------------------------------------------------------------------
template <int EPI>
__global__ __launch_bounds__(512, 2) void gemm256_k(const bf16* __restrict__ A,
                                                    const bf16* __restrict__ Bt,
                                                    const float* __restrict__ bias,
                                                    void* __restrict__ o0,
                                                    int K, int N) {
  __shared__ bf16 As[2][2][128 * 64];
  __shared__ bf16 Bs[2][2][128 * 64];
  const int tid = threadIdx.x;
  const int lane = tid & 63, w = tid >> 6;
  const int wr = w >> 2, wc = w & 3;
  const int l15 = lane & 15, l4 = lane >> 4;
  const int gx = gridDim.x;
  const int nwg = gx * gridDim.y;
  const int flat = blockIdx.x + blockIdx.y * gx;
  const int swz = (flat & 7) * (nwg >> 3) + (flat >> 3);
  const size_t bm = swz / gx, bn = swz % gx;
  const bf16* Ab = A + bm * 256 * (size_t)K;
  const bf16* Bb = Bt + bn * 256 * (size_t)K;

  const f32x4 zero4 = {0.f, 0.f, 0.f, 0.f};
  f32x4 acc[8][4];
  for (int m = 0; m < 8; ++m)
    for (int n = 0; n < 4; ++n) acc[m][n] = zero4;

  const int srow = tid >> 3;
  const int gck = ((tid & 7) ^ (srow & 7)) * 8;
  auto stA = [&](int buf, int half, int t) {
    const bf16* src = Ab + (size_t)(half * 128 + srow) * K + t * 64 + gck;
    bf16* dst = &As[buf][half][tid * 8];
    gl16(src, dst);
    gl16(src + (size_t)64 * K, dst + 4096);
  };
  auto stB = [&](int buf, int half, int t) {
    const bf16* src = Bb + (size_t)(half * 128 + srow) * K + t * 64 + gck;
    bf16* dst = &Bs[buf][half][tid * 8];
    gl16(src, dst);
    gl16(src + (size_t)64 * K, dst + 4096);
  };

  const int xr = l15 & 7;
  const int ca0 = (l4 ^ xr) * 8, ca1 = ((4 + l4) ^ xr) * 8;
  bf16x8 af[4][2];
  bf16x8 bfr[2][2][2];
  const int brow0 = (wc & 1) * 64;
  auto ldA = [&](int buf, int mh) {
#pragma unroll
    for (int i = 0; i < 4; ++i) {
      const int r = mh * 64 + i * 16 + l15;
      af[i][0] = *(const bf16x8*)&As[buf][wr][r * 64 + ca0];
      af[i][1] = *(const bf16x8*)&As[buf][wr][r * 64 + ca1];
    }
  };
  auto ldB = [&](int buf, int nh) {
#pragma unroll
    for (int j = 0; j < 2; ++j) {
      const int r = brow0 + (nh * 2 + j) * 16 + l15;
      bfr[nh][j][0] = *(const bf16x8*)&Bs[buf][wc >> 1][r * 64 + ca0];
      bfr[nh][j][1] = *(const bf16x8*)&Bs[buf][wc >> 1][r * 64 + ca1];
    }
  };
  auto mfma16 = [&](int mh, int nh) {
#pragma unroll
    for (int i = 0; i < 4; ++i)
#pragma unroll
      for (int j = 0; j < 2; ++j) {
        acc[mh * 4 + i][nh * 2 + j] =
            MFMA16(af[i][0], bfr[nh][j][0], acc[mh * 4 + i][nh * 2 + j]);
        acc[mh * 4 + i][nh * 2 + j] =
            MFMA16(af[i][1], bfr[nh][j][1], acc[mh * 4 + i][nh * 2 + j]);
      }
  };

  auto ktile = [&](int buf, int tstage, bool dostage) {
    ldA(buf, 0); ldB(buf, 0); SCHED0();
    SBAR();
    LGKM_FENCE();
    PRIO(1); mfma16(0, 0); PRIO(0); SCHED0();
    SBAR();
    ldB(buf, 1); SCHED0();
    SBAR();
    LGKM_FENCE();
    PRIO(1); mfma16(0, 1); PRIO(0); SCHED0();
    SBAR();
    ldA(buf, 1);
    if (dostage) { stB(buf, 0, tstage); stB(buf, 1, tstage); }
    SCHED0();
    SBAR();
    LGKM_FENCE();
    PRIO(1); mfma16(1, 0); PRIO(0); SCHED0();
    SBAR();
    if (dostage) { stA(buf, 0, tstage); stA(buf, 1, tstage); }
    SCHED0();
    SBAR();
    PRIO(1); mfma16(1, 1); PRIO(0); SCHED0();
    SBAR();
  };

  const int nt = K >> 6;
  stA(0, 0, 0); stA(0, 1, 0); stB(0, 0, 0); stB(0, 1, 0);
  stA(1, 0, 1); stA(1, 1, 1); stB(1, 0, 1); stB(1, 1, 1);
  for (int t = 0; t < nt; ++t) {
    const int buf = t & 1;
    if (t < nt - 1) {
      asm volatile("s_waitcnt vmcnt(8)" ::: "memory");
    } else {
      asm volatile("s_waitcnt vmcnt(0)" ::: "memory");
    }
    SBAR(); SCHED0();
    ktile(buf, t + 2, t < nt - 2);
  }

  for (int m = 0; m < 8; ++m) {
    const int row0 = (int)bm * 256 + wr * 128 + m * 16 + l4 * 4;
    for (int n = 0; n < 4; ++n) {
      const int col = (int)bn * 256 + wc * 64 + n * 16 + l15;
      const float bv = bias[col];
      for (int r = 0; r < 4; ++r) {
        const int row = row0 + r;
        const float v = acc[m][n][r] + bv;
        const float gl = 0.5f * v * (1.0f + erff(v * 0.70710678118f));
        ((bf16*)o0)[(size_t)row * N + col] = (bf16)gl;
      }
    }
  }
}

// ---------------------------------------------------------------------------
// GEMM 128x64, BK=64, depth-2 counted-vmcnt pipeline (N=1024 outputs).
// EPI: 0 bias->bf16 | 2 bias+res->fp32
// ---------------------------------------------------------------------------
template <int EPI>
__global__ __launch_bounds__(256) void gemm64_k(const bf16* __restrict__ A,
                                                const bf16* __restrict__ Bt,
                                                const float* __restrict__ bias,
                                                const float* __restrict__ res,
                                                void* __restrict__ o0,
                                                int K, int N) {
  __shared__ bf16 As[2][128 * 64];
  __shared__ bf16 Bs[2][64 * 64];
  const int tid = threadIdx.x;
  const int lane = tid & 63, w = tid >> 6;
  const int l15 = lane & 15, l4 = lane >> 4;
  const int gx = gridDim.x;
  const int nwg = gx * gridDim.y;
  const int flat = blockIdx.x + blockIdx.y * gx;
  const int swz = (flat & 7) * (nwg >> 3) + (flat >> 3);
  const size_t bm = swz / gx, bn = swz % gx;
  const bf16* Ab = A + bm * 128 * (size_t)K;
  const bf16* Bb = Bt + bn * 64 * (size_t)K;

  const f32x4 zero4 = {0.f, 0.f, 0.f, 0.f};
  f32x4 acc[2][4];
  for (int m = 0; m < 2; ++m)
    for (int n = 0; n < 4; ++n) acc[m][n] = zero4;

  const int srow = lane >> 3;
  const int gck = ((lane & 7) ^ srow) * 8;
  auto stage = [&](int buf, int t) {
    const int kt = t * 64;
    for (int j = 0; j < 4; ++j) {
      const int row = w * 32 + j * 8 + srow;
      gl16(Ab + (size_t)row * K + kt + gck, As[buf] + (w * 256 + j * 64 + lane) * 8);
    }
    for (int j = 0; j < 2; ++j) {
      const int row = w * 16 + j * 8 + srow;
      gl16(Bb + (size_t)row * K + kt + gck, Bs[buf] + (w * 128 + j * 64 + lane) * 8);
    }
  };
  const int xr = l15 & 7;
  const int c0 = (l4 ^ xr) * 8, c1 = ((4 + l4) ^ xr) * 8;
  auto compute = [&](int buf) {
    bf16x8 af[2][2], bfr[4][2];
    for (int m = 0; m < 2; ++m) {
      const int ro = (w * 32 + m * 16 + l15) * 64;
      af[m][0] = *(const bf16x8*)&As[buf][ro + c0];
      af[m][1] = *(const bf16x8*)&As[buf][ro + c1];
    }
    for (int n = 0; n < 4; ++n) {
      const int ro = (n * 16 + l15) * 64;
      bfr[n][0] = *(const bf16x8*)&Bs[buf][ro + c0];
      bfr[n][1] = *(const bf16x8*)&Bs[buf][ro + c1];
    }
    PRIO(1);
    for (int m = 0; m < 2; ++m)
      for (int n = 0; n < 4; ++n) {
        acc[m][n] = MFMA16(af[m][0], bfr[n][0], acc[m][n]);
        acc[m][n] = MFMA16(af[m][1], bfr[n][1], acc[m][n]);
      }
    PRIO(0);
  };

  const int nt = K >> 6;
  stage(0, 0);
  stage(1, 1);
  int cur = 0;
  for (int t = 0; t < nt - 2; ++t) {
    asm volatile("s_waitcnt vmcnt(6)" ::: "memory");
    SBAR(); SCHED0();
    compute(cur);
    SCHED0(); SBAR(); SCHED0();
    stage(cur, t + 2);
    cur ^= 1;
  }
  asm volatile("s_waitcnt vmcnt(6)" ::: "memory");
  SBAR(); SCHED0();
  compute(cur);
  cur ^= 1;
  asm volatile("s_waitcnt vmcnt(0)" ::: "memory");
  SBAR(); SCHED0();
  compute(cur);

  for (int m = 0; m < 2; ++m) {
    const int row0 = (int)bm * 128 + w * 32 + m * 16 + l4 * 4;
    for (int n = 0; n < 4; ++n) {
      const int col = (int)bn * 64 + n * 16 + l15;
      const float bv = bias[col];
      for (int r = 0; r < 4; ++r) {
        const int row = row0 + r;
        const float v = acc[m][n][r] + bv;
        if constexpr (EPI == 0) {
          ((bf16*)o0)[(size_t)row * N + col] = (bf16)v;
        } else {
          ((float*)o0)[(size_t)row * N + col] = v + res[(size_t)row * N + col];
        }
      }
    }
  }
}

// ---------------------------------------------------------------------------
// Causal flash attention with cooperative LDS K/V staging (unchanged).
// ---------------------------------------------------------------------------
__global__ __launch_bounds__(512) void attn_k(const bf16* __restrict__ Q,
                                              const bf16* __restrict__ Kb,
                                              const bf16* __restrict__ Vt,
                                              bf16* __restrict__ O) {
  __shared__ bf16 Ks[2][64 * 64];
  __shared__ bf16 Vs[2][64 * 64];
  __shared__ bf16 Plds[8][16][72];
  const int bx = blockIdx.x, bh = blockIdx.y;
  const int b = bh >> 4, h = bh & 15;
  const int tid = threadIdx.x, lane = tid & 63, w = tid >> 6;
  const int myqt = (w < 4) ? bx : (15 - bx);
  const int qbase = myqt * 64 + (w & 3) * 16;
  const int l15 = lane & 15, l4 = lane >> 4;
  const int nt = 16 - bx;

  const bf16* Qp = Q + (size_t)(b * 1024 + qbase + l15) * 1024 + h * 64 + l4 * 8;
  bf16x8 qf0 = *(const bf16x8*)Qp;
  bf16x8 qf1 = *(const bf16x8*)(Qp + 32);
  for (int i = 0; i < 8; ++i) {
    qf0[i] = (bf16)((float)qf0[i] * 0.125f);
    qf1[i] = (bf16)((float)qf1[i] * 0.125f);
  }
  bf16x8 onesf;
  for (int i = 0; i < 8; ++i) onesf[i] = (bf16)1.0f;

  const f32x4 zero4 = {0.f, 0.f, 0.f, 0.f};
  f32x4 o[4], ol;
  float mrow[4];
  for (int d = 0; d < 4; ++d) o[d] = zero4;
  ol = zero4;
  for (int r = 0; r < 4; ++r) mrow[r] = -1e30f;

  const int qrow0 = qbase + l4 * 4;

  const int srow = tid >> 3;
  const int cg = (tid & 7) ^ (srow & 7);
  const bf16* Kg = Kb + (size_t)(b * 1024 + srow) * 1024 + h * 64 + cg * 8;
  const bf16* Vg = Vt + (size_t)(bh * 64 + srow) * 1024 + cg * 8;
  auto stage = [&](int buf, int t) {
    gl16(Kg + (size_t)t * 64 * 1024, Ks[buf] + tid * 8);
    gl16(Vg + t * 64, Vs[buf] + tid * 8);
  };

  const int xr = l15 & 7;
  const int fc0 = (l4 ^ xr) * 8, fc1 = ((4 + l4) ^ xr) * 8;

  auto compute = [&](int buf, int kt) {
    const int kbase = kt * 64;
    f32x4 s[4];
    for (int n = 0; n < 4; ++n) s[n] = zero4;
    PRIO(1);
    for (int n = 0; n < 4; ++n) {
      const int ro = (n * 16 + l15) * 64;
      const bf16x8 kf0 = *(const bf16x8*)&Ks[buf][ro + fc0];
      const bf16x8 kf1 = *(const bf16x8*)&Ks[buf][ro + fc1];
      s[n] = MFMA16(qf0, kf0, s[n]);
      s[n] = MFMA16(qf1, kf1, s[n]);
    }
    PRIO(0);
    if (kt == myqt) {
      for (int n = 0; n < 4; ++n) {
        const int kc = kbase + n * 16 + l15;
        for (int r = 0; r < 4; ++r)
          if (kc > qrow0 + r) s[n][r] = -1e30f;
      }
    }
    float mx[4];
    for (int r = 0; r < 4; ++r)
      mx[r] = fmaxf(fmaxf(s[0][r], s[1][r]), fmaxf(s[2][r], s[3][r]));
    for (int d0 = 1; d0 < 16; d0 <<= 1)
      for (int r = 0; r < 4; ++r) mx[r] = fmaxf(mx[r], __shfl_xor(mx[r], d0));
    float alpha[4];
    for (int r = 0; r < 4; ++r) {
      const float mnew = fmaxf(mrow[r], mx[r]);
      alpha[r] = __expf(mrow[r] - mnew);
      mrow[r] = mnew;
    }
    for (int n = 0; n < 4; ++n)
      for (int r = 0; r < 4; ++r) s[n][r] = __expf(s[n][r] - mrow[r]);
    for (int d = 0; d < 4; ++d)
      for (int r = 0; r < 4; ++r) o[d][r] *= alpha[r];
    for (int r = 0; r < 4; ++r) ol[r] *= alpha[r];

    LGKM_FENCE();
    for (int r = 0; r < 4; ++r)
      for (int n = 0; n < 4; ++n)
        Plds[w][l4 * 4 + r][n * 16 + l15] = (bf16)s[n][r];
    LGKM_FENCE();
    const bf16x8 pf0 = *(const bf16x8*)&Plds[w][l15][l4 * 8];
    const bf16x8 pf1 = *(const bf16x8*)&Plds[w][l15][32 + l4 * 8];

    PRIO(1);
    for (int d = 0; d < 4; ++d) {
      const int ro = (d * 16 + l15) * 64;
      const bf16x8 vf0 = *(const bf16x8*)&Vs[buf][ro + fc0];
      const bf16x8 vf1 = *(const bf16x8*)&Vs[buf][ro + fc1];
      o[d] = MFMA16(pf0, vf0, o[d]);
      o[d] = MFMA16(pf1, vf1, o[d]);
    }
    ol = MFMA16(pf0, onesf, ol);
    ol = MFMA16(pf1, onesf, ol);
    PRIO(0);
  };

  stage(0, 0);
  stage(1, 1);
  int cur = 0;
  for (int t = 0; t < nt - 2; ++t) {
    asm volatile("s_waitcnt vmcnt(2)" ::: "memory");
    SBAR(); SCHED0();
    if (t <= myqt) compute(cur, t);
    SCHED0(); SBAR(); SCHED0();
    stage(cur, t + 2);
    cur ^= 1;
  }
  asm volatile("s_waitcnt vmcnt(2)" ::: "memory");
  SBAR(); SCHED0();
  if (nt - 2 <= myqt) compute(cur, nt - 2);
  cur ^= 1;
  asm volatile("s_waitcnt vmcnt(0)" ::: "memory");
  SBAR(); SCHED0();
  if (nt - 1 <= myqt) compute(cur, nt - 1);

  for (int r = 0; r < 4; ++r) {
    const float inv = 1.0f / ol[r];
    for (int d = 0; d < 4; ++d) {
      O[(size_t)(b * 1024 + qbase + l4 * 4 + r) * 1024 + h * 64 + d * 16 + l15] =
          (bf16)(o[d][r] * inv);
    }
  }
}

// ---------------------------------------------------------------------------
extern "C" void kernel_launch(void* const* d_in, const int* in_sizes, int n_in,
                              void* d_out, int out_size, void* d_ws, size_t ws_size,
                              hipStream_t stream) {
  const float* x_enc = (const float*)d_in[0];
  const float* x     = (const float*)d_in[1];
  const float* ln1_g = (const float*)d_in[2];
  const float* ln1_b = (const float*)d_in[3];
  const float* ln2_g = (const float*)d_in[4];
  const float* ln2_b = (const float*)d_in[5];
  const float* sa_wq = (const float*)d_in[6];  const float* sa_bq = (const float*)d_in[7];
  const float* sa_wk = (const float*)d_in[8];  const float* sa_bk = (const float*)d_in[9];
  const float* sa_wv = (const float*)d_in[10]; const float* sa_bv = (const float*)d_in[11];
  const float* sa_wo = (const float*)d_in[12]; const float* sa_bo = (const float*)d_in[13];
  const float* ca_wq = (const float*)d_in[14]; const float* ca_bq = (const float*)d_in[15];
  const float* ca_wk = (const float*)d_in[16]; const float* ca_bk = (const float*)d_in[17];
  const float* ca_wv = (const float*)d_in[18]; const float* ca_bv = (const float*)d_in[19];
  const float* ca_wo = (const float*)d_in[20]; const float* ca_bo = (const float*)d_in[21];
  const float* mlp_w1 = (const float*)d_in[22]; const float* mlp_b1 = (const float*)d_in[23];
  const float* mlp_w2 = (const float*)d_in[24]; const float* mlp_b2 = (const float*)d_in[25];

  char* ws = (char*)d_ws;
  size_t off = 0;
  auto take = [&](size_t bytes) { char* p = ws + off; off += (bytes + 255) & ~(size_t)255; return p; };

  bf16* wt8 = (bf16*)take((size_t)8 * 1024 * 1024 * 2);
  bf16* w1t   = (bf16*)take((size_t)4096 * 1024 * 2);
  bf16* w2t   = (bf16*)take((size_t)1024 * 4096 * 2);
  bf16* lnbuf = (bf16*)take((size_t)4096 * 1024 * 2);
  bf16* xe_bf = (bf16*)take((size_t)4096 * 1024 * 2);
  bf16* Qb    = (bf16*)take((size_t)4096 * 1024 * 2);
  bf16* Kbf   = (bf16*)take((size_t)4096 * 1024 * 2);
  bf16* Vpb   = (bf16*)take((size_t)4096 * 1024 * 2);  // V plain
  bf16* Vtb   = (bf16*)take((size_t)4096 * 1024 * 2);  // V transposed
  bf16* AOb   = (bf16*)take((size_t)4096 * 1024 * 2);
  float* x1   = (float*)take((size_t)4096 * 1024 * 4);
  float* x2   = (float*)take((size_t)4096 * 1024 * 4);
  bf16* Hb    = (bf16*)take((size_t)4096 * 4096 * 2);
  float* bq3  = (float*)take((size_t)3072 * 4);
  float* bkv2 = (float*)take((size_t)2048 * 4);

  bf16* wt[8];
  for (int i = 0; i < 8; ++i) wt[i] = wt8 + (size_t)i * 1024 * 1024;

  const dim3 blk(256);
  WPtrs wp = {{sa_wq, sa_wk, sa_wv, sa_wo, ca_wq, ca_wk, ca_wv, ca_wo}};
  wtrans8_k<<<dim3(32, 32, 8), blk, 0, stream>>>(wp, wt8);
  wtrans_k<<<dim3(128, 32), blk, 0, stream>>>(mlp_w1, w1t, 1024, 4096);
  wtrans_k<<<dim3(32, 128), blk, 0, stream>>>(mlp_w2, w2t, 4096, 1024);
  tobf_k<<<4096, blk, 0, stream>>>(x_enc, xe_bf);
  B5 bp = {{sa_bq, sa_bk, sa_bv, ca_bk, ca_bv}};
  bpack_k<<<5, blk, 0, stream>>>(bp, bq3, bkv2);

  // x = x + SelfAttn(ln1(x)) — fused QKV projection, V plain + transpose
  ln_k<<<4096, blk, 0, stream>>>(x, ln1_g, ln1_b, lnbuf);
  gemm_k<4><<<dim3(24, 32), blk, 0, stream>>>(lnbuf, wt[0], bq3, nullptr,
                                              Qb, Kbf, Vpb, 1024, 3072);
  vtrans_k<<<dim3(16, 64), dim3(512), 0, stream>>>(Vpb, Vtb);
  attn_k<<<dim3(8, 64), dim3(512), 0, stream>>>(Qb, Kbf, Vtb, AOb);
  gemm64_k<2><<<dim3(16, 32), blk, 0, stream>>>(AOb, wt[3], sa_bo, x, x1, 1024, 1024);

  // x = x + CrossAttn(ln1(x), x_encoder) — fused KV, V plain + transpose
  ln_k<<<4096, blk, 0, stream>>>(x1, ln1_g, ln1_b, lnbuf);
  gemm64_k<0><<<dim3(16, 32), blk, 0, stream>>>(lnbuf, wt[4], ca_bq, nullptr, Qb, 1024, 1024);
  gemm_k<5><<<dim3(16, 32), blk, 0, stream>>>(xe_bf, wt[5], bkv2, nullptr,
                                              Kbf, Vpb, nullptr, 1024, 2048);
  vtrans_k<<<dim3(16, 64), dim3(512), 0, stream>>>(Vpb, Vtb);
  attn_k<<<dim3(8, 64), dim3(512), 0, stream>>>(Qb, Kbf, Vtb, AOb);
  gemm64_k<2><<<dim3(16, 32), blk, 0, stream>>>(AOb, wt[7], ca_bo, x1, x2, 1024, 1024);

  // x = x + MLP(ln2(x)) — MLP1 on 256^2 8-phase (isolated diagnostic)
  ln_k<<<4096, blk, 0, stream>>>(x2, ln2_g, ln2_b, lnbuf);
  gemm256_k<3><<<dim3(16, 16), dim3(512), 0, stream>>>(lnbuf, w1t, mlp_b1,
                                                       Hb, 1024, 4096);
  gemm64_k<2><<<dim3(16, 32), blk, 0, stream>>>(Hb, w2t, mlp_b2, x2,
                                                (float*)d_out, 4096, 1024);

  (void)in_sizes; (void)n_in; (void)out_size; (void)ws_size;
}

// Round 9
// 353.950 us; speedup vs baseline: 1.2088x; 1.0791x over previous
//
#include <hip/hip_runtime.h>
#include <hip/hip_bf16.h>

typedef __bf16 bf16;
typedef __attribute__((ext_vector_type(8))) __bf16 bf16x8;
typedef __attribute__((ext_vector_type(4))) float f32x4;

#define MFMA16(a, b, c) __builtin_amdgcn_mfma_f32_16x16x32_bf16(a, b, c, 0, 0, 0)

#define LGKM_FENCE()                                      \
  do {                                                    \
    asm volatile("s_waitcnt lgkmcnt(0)" ::: "memory");    \
    __builtin_amdgcn_sched_barrier(0);                    \
  } while (0)

#define SCHED0() __builtin_amdgcn_sched_barrier(0)
#define SBAR() __builtin_amdgcn_s_barrier()
#define PRIO(x) __builtin_amdgcn_s_setprio(x)

typedef __attribute__((address_space(1))) void gvoid;
typedef __attribute__((address_space(3))) void lvoid;
__device__ __forceinline__ void gl16(const bf16* g, bf16* l) {
  __builtin_amdgcn_global_load_lds((gvoid*)g, (lvoid*)l, 16, 0, 0);
}

// Problem geometry: B=4, T=1024, D=1024, H=16, HD=64, DFF=4096, M=4096

// ---------------------------------------------------------------------------
struct WPtrs { const float* p[8]; };

__global__ __launch_bounds__(256) void wtrans8_k(WPtrs wp, bf16* __restrict__ dst) {
  const float* w = wp.p[blockIdx.z];
  bf16* wt = dst + (size_t)blockIdx.z * 1024 * 1024;
  __shared__ float t[32][33];
  const int tx = threadIdx.x & 31, ty = threadIdx.x >> 5;
  const int nb = blockIdx.x * 32, kb = blockIdx.y * 32;
  for (int i = 0; i < 4; ++i)
    t[ty + i * 8][tx] = w[(size_t)(kb + ty + i * 8) * 1024 + nb + tx];
  __syncthreads();
  for (int i = 0; i < 4; ++i)
    wt[(size_t)(nb + ty + i * 8) * 1024 + kb + tx] = (bf16)t[tx][ty + i * 8];
}

__global__ __launch_bounds__(256) void wtrans_k(const float* __restrict__ w,
                                                bf16* __restrict__ wt,
                                                int K, int N) {
  __shared__ float t[32][33];
  const int tx = threadIdx.x & 31, ty = threadIdx.x >> 5;
  const int nb = blockIdx.x * 32, kb = blockIdx.y * 32;
  for (int i = 0; i < 4; ++i)
    t[ty + i * 8][tx] = w[(size_t)(kb + ty + i * 8) * N + nb + tx];
  __syncthreads();
  for (int i = 0; i < 4; ++i)
    wt[(size_t)(nb + ty + i * 8) * K + kb + tx] = (bf16)t[tx][ty + i * 8];
}

// ---------------------------------------------------------------------------
__global__ __launch_bounds__(256) void tobf_k(const float* __restrict__ in,
                                              bf16* __restrict__ out) {
  const int i = blockIdx.x * 256 + threadIdx.x;
  const float4 v = ((const float4*)in)[i];
  bf16* o = out + (size_t)i * 4;
  o[0] = (bf16)v.x; o[1] = (bf16)v.y; o[2] = (bf16)v.z; o[3] = (bf16)v.w;
}

struct B5 { const float* s[5]; };
__global__ __launch_bounds__(256) void bpack_k(B5 bp, float* __restrict__ bq3,
                                               float* __restrict__ bkv2) {
  const int i = blockIdx.x;
  float* d = (i < 3) ? bq3 + i * 1024 : bkv2 + (i - 3) * 1024;
  ((float4*)d)[threadIdx.x] = ((const float4*)bp.s[i])[threadIdx.x];
}

// ---------------------------------------------------------------------------
// V transpose: Vp[M=4096][1024] (head h in cols h*64..+63) ->
// Vt[B*H][HD=64][T=1024]. 64x64 LDS tiles, coalesced 16B on both sides.
// ---------------------------------------------------------------------------
__global__ __launch_bounds__(512) void vtrans_k(const bf16* __restrict__ Vp,
                                                bf16* __restrict__ Vt) {
  __shared__ bf16 tl[64][72];
  const int tt = blockIdx.x, bh = blockIdx.y;
  const int b = bh >> 4, h = bh & 15;
  const int tid = threadIdx.x;
  const int row = tid >> 3, ck = tid & 7;
  *(bf16x8*)&tl[row][ck * 8] =
      *(const bf16x8*)&Vp[(size_t)(b * 1024 + tt * 64 + row) * 1024 + h * 64 + ck * 8];
  __syncthreads();
  const int hd = tid >> 3, tc = tid & 7;
  bf16 tmp[8];
#pragma unroll
  for (int e = 0; e < 8; ++e) tmp[e] = tl[tc * 8 + e][hd];
  *(bf16x8*)&Vt[(size_t)(bh * 64 + hd) * 1024 + tt * 64 + tc * 8] = *(bf16x8*)tmp;
}

// ---------------------------------------------------------------------------
__global__ __launch_bounds__(256) void ln_k(const float* __restrict__ x,
                                            const float* __restrict__ g,
                                            const float* __restrict__ bta,
                                            bf16* __restrict__ out) {
  const int row = blockIdx.x, tid = threadIdx.x;
  const float4 v = ((const float4*)(x + (size_t)row * 1024))[tid];
  float s = v.x + v.y + v.z + v.w;
  float sq = v.x * v.x + v.y * v.y + v.z * v.z + v.w * v.w;
  for (int d = 1; d < 64; d <<= 1) { s += __shfl_xor(s, d); sq += __shfl_xor(sq, d); }
  __shared__ float rs[4], rq[4];
  const int w = tid >> 6, lane = tid & 63;
  if (lane == 0) { rs[w] = s; rq[w] = sq; }
  __syncthreads();
  s = rs[0] + rs[1] + rs[2] + rs[3];
  sq = rq[0] + rq[1] + rq[2] + rq[3];
  const float mean = s * (1.0f / 1024.0f);
  const float var = sq * (1.0f / 1024.0f) - mean * mean;
  const float rstd = rsqrtf(var + 1e-5f);
  const float4 gv = ((const float4*)g)[tid];
  const float4 bv = ((const float4*)bta)[tid];
  bf16* o = out + (size_t)row * 1024 + tid * 4;
  o[0] = (bf16)((v.x - mean) * rstd * gv.x + bv.x);
  o[1] = (bf16)((v.y - mean) * rstd * gv.y + bv.y);
  o[2] = (bf16)((v.z - mean) * rstd * gv.z + bv.z);
  o[3] = (bf16)((v.w - mean) * rstd * gv.w + bv.w);
}

// ---------------------------------------------------------------------------
// GEMM 128x128, BK=64, 4 waves, depth-2 counted-vmcnt pipeline, XOR-swizzled
// LDS. EPI: 0 bias->bf16 | 2 bias+res->fp32 | 3 bias+GELU->bf16
//      4 fused QKV (Q,K,V all plain bf16[M,1024]) | 5 fused KV (plain)
// ---------------------------------------------------------------------------
template <int EPI>
__global__ __launch_bounds__(256) void gemm_k(const bf16* __restrict__ A,
                                              const bf16* __restrict__ Bt,
                                              const float* __restrict__ bias,
                                              const float* __restrict__ res,
                                              void* __restrict__ o0,
                                              void* __restrict__ o1,
                                              void* __restrict__ o2,
                                              int K, int N) {
  __shared__ bf16 As[2][128 * 64];
  __shared__ bf16 Bs[2][128 * 64];
  const int tid = threadIdx.x;
  const int lane = tid & 63, w = tid >> 6;
  const int wr = w >> 1, wc = w & 1;
  const int l15 = lane & 15, l4 = lane >> 4;
  const int gx = gridDim.x;
  const int nwg = gx * gridDim.y;
  const int flat = blockIdx.x + blockIdx.y * gx;
  const int swz = (flat & 7) * (nwg >> 3) + (flat >> 3);
  const size_t bm = swz / gx, bn = swz % gx;
  const bf16* Ab = A + bm * 128 * (size_t)K;
  const bf16* Bb = Bt + bn * 128 * (size_t)K;

  const f32x4 zero4 = {0.f, 0.f, 0.f, 0.f};
  f32x4 acc[4][4];
  for (int m = 0; m < 4; ++m)
    for (int n = 0; n < 4; ++n) acc[m][n] = zero4;

  const int srow = lane >> 3;
  const int gck = ((lane & 7) ^ srow) * 8;
  auto stage = [&](int buf, int t) {
    const int kt = t * 64;
    for (int j = 0; j < 4; ++j) {
      const int row = w * 32 + j * 8 + srow;
      bf16* la = As[buf] + (w * 256 + j * 64 + lane) * 8;
      bf16* lb = Bs[buf] + (w * 256 + j * 64 + lane) * 8;
      gl16(Ab + (size_t)row * K + kt + gck, la);
      gl16(Bb + (size_t)row * K + kt + gck, lb);
    }
  };
  const int xr = l15 & 7;
  const int c0 = (l4 ^ xr) * 8, c1 = ((4 + l4) ^ xr) * 8;
  auto compute = [&](int buf) {
    bf16x8 af[4][2], bfr[4][2];
    for (int m = 0; m < 4; ++m) {
      const int ro = (wr * 64 + m * 16 + l15) * 64;
      af[m][0] = *(const bf16x8*)&As[buf][ro + c0];
      af[m][1] = *(const bf16x8*)&As[buf][ro + c1];
    }
    for (int n = 0; n < 4; ++n) {
      const int ro = (wc * 64 + n * 16 + l15) * 64;
      bfr[n][0] = *(const bf16x8*)&Bs[buf][ro + c0];
      bfr[n][1] = *(const bf16x8*)&Bs[buf][ro + c1];
    }
    PRIO(1);
    for (int m = 0; m < 4; ++m)
      for (int n = 0; n < 4; ++n) {
        acc[m][n] = MFMA16(af[m][0], bfr[n][0], acc[m][n]);
        acc[m][n] = MFMA16(af[m][1], bfr[n][1], acc[m][n]);
      }
    PRIO(0);
  };

  const int nt = K >> 6;
  stage(0, 0);
  stage(1, 1);
  int cur = 0;
  for (int t = 0; t < nt - 2; ++t) {
    asm volatile("s_waitcnt vmcnt(8)" ::: "memory");
    SBAR(); SCHED0();
    compute(cur);
    SCHED0(); SBAR(); SCHED0();
    stage(cur, t + 2);
    cur ^= 1;
  }
  asm volatile("s_waitcnt vmcnt(8)" ::: "memory");
  SBAR(); SCHED0();
  compute(cur);
  cur ^= 1;
  asm volatile("s_waitcnt vmcnt(0)" ::: "memory");
  SBAR(); SCHED0();
  compute(cur);

  for (int m = 0; m < 4; ++m) {
    const int row0 = (int)bm * 128 + wr * 64 + m * 16 + l4 * 4;
    for (int n = 0; n < 4; ++n) {
      const int col = (int)bn * 128 + wc * 64 + n * 16 + l15;
      const float bv = bias[col];
      for (int r = 0; r < 4; ++r) {
        const int row = row0 + r;
        const float v = acc[m][n][r] + bv;
        if constexpr (EPI == 0) {
          ((bf16*)o0)[(size_t)row * N + col] = (bf16)v;
        } else if constexpr (EPI == 2) {
          ((float*)o0)[(size_t)row * N + col] = v + res[(size_t)row * N + col];
        } else if constexpr (EPI == 3) {
          const float gl = 0.5f * v * (1.0f + erff(v * 0.70710678118f));
          ((bf16*)o0)[(size_t)row * N + col] = (bf16)gl;
        } else {
          const int which = col >> 10, c = col & 1023;
          bf16* op = (bf16*)(which == 0 ? o0 : (which == 1 ? o1 : o2));
          op[(size_t)row * 1024 + c] = (bf16)v;
        }
      }
    }
  }
}

// ---------------------------------------------------------------------------
// GEMM 128x64, BK=64, depth-2 counted-vmcnt pipeline (N=1024 outputs).
// EPI: 0 bias->bf16 | 2 bias+res->fp32
// ---------------------------------------------------------------------------
template <int EPI>
__global__ __launch_bounds__(256) void gemm64_k(const bf16* __restrict__ A,
                                                const bf16* __restrict__ Bt,
                                                const float* __restrict__ bias,
                                                const float* __restrict__ res,
                                                void* __restrict__ o0,
                                                int K, int N) {
  __shared__ bf16 As[2][128 * 64];
  __shared__ bf16 Bs[2][64 * 64];
  const int tid = threadIdx.x;
  const int lane = tid & 63, w = tid >> 6;
  const int l15 = lane & 15, l4 = lane >> 4;
  const int gx = gridDim.x;
  const int nwg = gx * gridDim.y;
  const int flat = blockIdx.x + blockIdx.y * gx;
  const int swz = (flat & 7) * (nwg >> 3) + (flat >> 3);
  const size_t bm = swz / gx, bn = swz % gx;
  const bf16* Ab = A + bm * 128 * (size_t)K;
  const bf16* Bb = Bt + bn * 64 * (size_t)K;

  const f32x4 zero4 = {0.f, 0.f, 0.f, 0.f};
  f32x4 acc[2][4];
  for (int m = 0; m < 2; ++m)
    for (int n = 0; n < 4; ++n) acc[m][n] = zero4;

  const int srow = lane >> 3;
  const int gck = ((lane & 7) ^ srow) * 8;
  auto stage = [&](int buf, int t) {
    const int kt = t * 64;
    for (int j = 0; j < 4; ++j) {
      const int row = w * 32 + j * 8 + srow;
      gl16(Ab + (size_t)row * K + kt + gck, As[buf] + (w * 256 + j * 64 + lane) * 8);
    }
    for (int j = 0; j < 2; ++j) {
      const int row = w * 16 + j * 8 + srow;
      gl16(Bb + (size_t)row * K + kt + gck, Bs[buf] + (w * 128 + j * 64 + lane) * 8);
    }
  };
  const int xr = l15 & 7;
  const int c0 = (l4 ^ xr) * 8, c1 = ((4 + l4) ^ xr) * 8;
  auto compute = [&](int buf) {
    bf16x8 af[2][2], bfr[4][2];
    for (int m = 0; m < 2; ++m) {
      const int ro = (w * 32 + m * 16 + l15) * 64;
      af[m][0] = *(const bf16x8*)&As[buf][ro + c0];
      af[m][1] = *(const bf16x8*)&As[buf][ro + c1];
    }
    for (int n = 0; n < 4; ++n) {
      const int ro = (n * 16 + l15) * 64;
      bfr[n][0] = *(const bf16x8*)&Bs[buf][ro + c0];
      bfr[n][1] = *(const bf16x8*)&Bs[buf][ro + c1];
    }
    PRIO(1);
    for (int m = 0; m < 2; ++m)
      for (int n = 0; n < 4; ++n) {
        acc[m][n] = MFMA16(af[m][0], bfr[n][0], acc[m][n]);
        acc[m][n] = MFMA16(af[m][1], bfr[n][1], acc[m][n]);
      }
    PRIO(0);
  };

  const int nt = K >> 6;
  stage(0, 0);
  stage(1, 1);
  int cur = 0;
  for (int t = 0; t < nt - 2; ++t) {
    asm volatile("s_waitcnt vmcnt(6)" ::: "memory");
    SBAR(); SCHED0();
    compute(cur);
    SCHED0(); SBAR(); SCHED0();
    stage(cur, t + 2);
    cur ^= 1;
  }
  asm volatile("s_waitcnt vmcnt(6)" ::: "memory");
  SBAR(); SCHED0();
  compute(cur);
  cur ^= 1;
  asm volatile("s_waitcnt vmcnt(0)" ::: "memory");
  SBAR(); SCHED0();
  compute(cur);

  for (int m = 0; m < 2; ++m) {
    const int row0 = (int)bm * 128 + w * 32 + m * 16 + l4 * 4;
    for (int n = 0; n < 4; ++n) {
      const int col = (int)bn * 64 + n * 16 + l15;
      const float bv = bias[col];
      for (int r = 0; r < 4; ++r) {
        const int row = row0 + r;
        const float v = acc[m][n][r] + bv;
        if constexpr (EPI == 0) {
          ((bf16*)o0)[(size_t)row * N + col] = (bf16)v;
        } else {
          ((float*)o0)[(size_t)row * N + col] = v + res[(size_t)row * N + col];
        }
      }
    }
  }
}

// ---------------------------------------------------------------------------
// Causal flash attention with cooperative LDS K/V staging (unchanged).
// ---------------------------------------------------------------------------
__global__ __launch_bounds__(512) void attn_k(const bf16* __restrict__ Q,
                                              const bf16* __restrict__ Kb,
                                              const bf16* __restrict__ Vt,
                                              bf16* __restrict__ O) {
  __shared__ bf16 Ks[2][64 * 64];
  __shared__ bf16 Vs[2][64 * 64];
  __shared__ bf16 Plds[8][16][72];
  const int bx = blockIdx.x, bh = blockIdx.y;
  const int b = bh >> 4, h = bh & 15;
  const int tid = threadIdx.x, lane = tid & 63, w = tid >> 6;
  const int myqt = (w < 4) ? bx : (15 - bx);
  const int qbase = myqt * 64 + (w & 3) * 16;
  const int l15 = lane & 15, l4 = lane >> 4;
  const int nt = 16 - bx;

  const bf16* Qp = Q + (size_t)(b * 1024 + qbase + l15) * 1024 + h * 64 + l4 * 8;
  bf16x8 qf0 = *(const bf16x8*)Qp;
  bf16x8 qf1 = *(const bf16x8*)(Qp + 32);
  for (int i = 0; i < 8; ++i) {
    qf0[i] = (bf16)((float)qf0[i] * 0.125f);
    qf1[i] = (bf16)((float)qf1[i] * 0.125f);
  }
  bf16x8 onesf;
  for (int i = 0; i < 8; ++i) onesf[i] = (bf16)1.0f;

  const f32x4 zero4 = {0.f, 0.f, 0.f, 0.f};
  f32x4 o[4], ol;
  float mrow[4];
  for (int d = 0; d < 4; ++d) o[d] = zero4;
  ol = zero4;
  for (int r = 0; r < 4; ++r) mrow[r] = -1e30f;

  const int qrow0 = qbase + l4 * 4;

  const int srow = tid >> 3;
  const int cg = (tid & 7) ^ (srow & 7);
  const bf16* Kg = Kb + (size_t)(b * 1024 + srow) * 1024 + h * 64 + cg * 8;
  const bf16* Vg = Vt + (size_t)(bh * 64 + srow) * 1024 + cg * 8;
  auto stage = [&](int buf, int t) {
    gl16(Kg + (size_t)t * 64 * 1024, Ks[buf] + tid * 8);
    gl16(Vg + t * 64, Vs[buf] + tid * 8);
  };

  const int xr = l15 & 7;
  const int fc0 = (l4 ^ xr) * 8, fc1 = ((4 + l4) ^ xr) * 8;

  auto compute = [&](int buf, int kt) {
    const int kbase = kt * 64;
    f32x4 s[4];
    for (int n = 0; n < 4; ++n) s[n] = zero4;
    PRIO(1);
    for (int n = 0; n < 4; ++n) {
      const int ro = (n * 16 + l15) * 64;
      const bf16x8 kf0 = *(const bf16x8*)&Ks[buf][ro + fc0];
      const bf16x8 kf1 = *(const bf16x8*)&Ks[buf][ro + fc1];
      s[n] = MFMA16(qf0, kf0, s[n]);
      s[n] = MFMA16(qf1, kf1, s[n]);
    }
    PRIO(0);
    if (kt == myqt) {
      for (int n = 0; n < 4; ++n) {
        const int kc = kbase + n * 16 + l15;
        for (int r = 0; r < 4; ++r)
          if (kc > qrow0 + r) s[n][r] = -1e30f;
      }
    }
    float mx[4];
    for (int r = 0; r < 4; ++r)
      mx[r] = fmaxf(fmaxf(s[0][r], s[1][r]), fmaxf(s[2][r], s[3][r]));
    for (int d0 = 1; d0 < 16; d0 <<= 1)
      for (int r = 0; r < 4; ++r) mx[r] = fmaxf(mx[r], __shfl_xor(mx[r], d0));
    float alpha[4];
    for (int r = 0; r < 4; ++r) {
      const float mnew = fmaxf(mrow[r], mx[r]);
      alpha[r] = __expf(mrow[r] - mnew);
      mrow[r] = mnew;
    }
    for (int n = 0; n < 4; ++n)
      for (int r = 0; r < 4; ++r) s[n][r] = __expf(s[n][r] - mrow[r]);
    for (int d = 0; d < 4; ++d)
      for (int r = 0; r < 4; ++r) o[d][r] *= alpha[r];
    for (int r = 0; r < 4; ++r) ol[r] *= alpha[r];

    LGKM_FENCE();
    for (int r = 0; r < 4; ++r)
      for (int n = 0; n < 4; ++n)
        Plds[w][l4 * 4 + r][n * 16 + l15] = (bf16)s[n][r];
    LGKM_FENCE();
    const bf16x8 pf0 = *(const bf16x8*)&Plds[w][l15][l4 * 8];
    const bf16x8 pf1 = *(const bf16x8*)&Plds[w][l15][32 + l4 * 8];

    PRIO(1);
    for (int d = 0; d < 4; ++d) {
      const int ro = (d * 16 + l15) * 64;
      const bf16x8 vf0 = *(const bf16x8*)&Vs[buf][ro + fc0];
      const bf16x8 vf1 = *(const bf16x8*)&Vs[buf][ro + fc1];
      o[d] = MFMA16(pf0, vf0, o[d]);
      o[d] = MFMA16(pf1, vf1, o[d]);
    }
    ol = MFMA16(pf0, onesf, ol);
    ol = MFMA16(pf1, onesf, ol);
    PRIO(0);
  };

  stage(0, 0);
  stage(1, 1);
  int cur = 0;
  for (int t = 0; t < nt - 2; ++t) {
    asm volatile("s_waitcnt vmcnt(2)" ::: "memory");
    SBAR(); SCHED0();
    if (t <= myqt) compute(cur, t);
    SCHED0(); SBAR(); SCHED0();
    stage(cur, t + 2);
    cur ^= 1;
  }
  asm volatile("s_waitcnt vmcnt(2)" ::: "memory");
  SBAR(); SCHED0();
  if (nt - 2 <= myqt) compute(cur, nt - 2);
  cur ^= 1;
  asm volatile("s_waitcnt vmcnt(0)" ::: "memory");
  SBAR(); SCHED0();
  if (nt - 1 <= myqt) compute(cur, nt - 1);

  for (int r = 0; r < 4; ++r) {
    const float inv = 1.0f / ol[r];
    for (int d = 0; d < 4; ++d) {
      O[(size_t)(b * 1024 + qbase + l4 * 4 + r) * 1024 + h * 64 + d * 16 + l15] =
          (bf16)(o[d][r] * inv);
    }
  }
}

// ---------------------------------------------------------------------------
extern "C" void kernel_launch(void* const* d_in, const int* in_sizes, int n_in,
                              void* d_out, int out_size, void* d_ws, size_t ws_size,
                              hipStream_t stream) {
  const float* x_enc = (const float*)d_in[0];
  const float* x     = (const float*)d_in[1];
  const float* ln1_g = (const float*)d_in[2];
  const float* ln1_b = (const float*)d_in[3];
  const float* ln2_g = (const float*)d_in[4];
  const float* ln2_b = (const float*)d_in[5];
  const float* sa_wq = (const float*)d_in[6];  const float* sa_bq = (const float*)d_in[7];
  const float* sa_wk = (const float*)d_in[8];  const float* sa_bk = (const float*)d_in[9];
  const float* sa_wv = (const float*)d_in[10]; const float* sa_bv = (const float*)d_in[11];
  const float* sa_wo = (const float*)d_in[12]; const float* sa_bo = (const float*)d_in[13];
  const float* ca_wq = (const float*)d_in[14]; const float* ca_bq = (const float*)d_in[15];
  const float* ca_wk = (const float*)d_in[16]; const float* ca_bk = (const float*)d_in[17];
  const float* ca_wv = (const float*)d_in[18]; const float* ca_bv = (const float*)d_in[19];
  const float* ca_wo = (const float*)d_in[20]; const float* ca_bo = (const float*)d_in[21];
  const float* mlp_w1 = (const float*)d_in[22]; const float* mlp_b1 = (const float*)d_in[23];
  const float* mlp_w2 = (const float*)d_in[24]; const float* mlp_b2 = (const float*)d_in[25];

  char* ws = (char*)d_ws;
  size_t off = 0;
  auto take = [&](size_t bytes) { char* p = ws + off; off += (bytes + 255) & ~(size_t)255; return p; };

  bf16* wt8 = (bf16*)take((size_t)8 * 1024 * 1024 * 2);
  bf16* w1t   = (bf16*)take((size_t)4096 * 1024 * 2);
  bf16* w2t   = (bf16*)take((size_t)1024 * 4096 * 2);
  bf16* lnbuf = (bf16*)take((size_t)4096 * 1024 * 2);
  bf16* xe_bf = (bf16*)take((size_t)4096 * 1024 * 2);
  bf16* Qb    = (bf16*)take((size_t)4096 * 1024 * 2);
  bf16* Kbf   = (bf16*)take((size_t)4096 * 1024 * 2);
  bf16* Vpb   = (bf16*)take((size_t)4096 * 1024 * 2);  // V plain
  bf16* Vtb   = (bf16*)take((size_t)4096 * 1024 * 2);  // V transposed
  bf16* AOb   = (bf16*)take((size_t)4096 * 1024 * 2);
  float* x1   = (float*)take((size_t)4096 * 1024 * 4);
  float* x2   = (float*)take((size_t)4096 * 1024 * 4);
  bf16* Hb    = (bf16*)take((size_t)4096 * 4096 * 2);
  float* bq3  = (float*)take((size_t)3072 * 4);
  float* bkv2 = (float*)take((size_t)2048 * 4);

  bf16* wt[8];
  for (int i = 0; i < 8; ++i) wt[i] = wt8 + (size_t)i * 1024 * 1024;

  const dim3 blk(256);
  WPtrs wp = {{sa_wq, sa_wk, sa_wv, sa_wo, ca_wq, ca_wk, ca_wv, ca_wo}};
  wtrans8_k<<<dim3(32, 32, 8), blk, 0, stream>>>(wp, wt8);
  wtrans_k<<<dim3(128, 32), blk, 0, stream>>>(mlp_w1, w1t, 1024, 4096);
  wtrans_k<<<dim3(32, 128), blk, 0, stream>>>(mlp_w2, w2t, 4096, 1024);
  tobf_k<<<4096, blk, 0, stream>>>(x_enc, xe_bf);
  B5 bp = {{sa_bq, sa_bk, sa_bv, ca_bk, ca_bv}};
  bpack_k<<<5, blk, 0, stream>>>(bp, bq3, bkv2);

  // x = x + SelfAttn(ln1(x)) — fused QKV projection, V plain + transpose
  ln_k<<<4096, blk, 0, stream>>>(x, ln1_g, ln1_b, lnbuf);
  gemm_k<4><<<dim3(24, 32), blk, 0, stream>>>(lnbuf, wt[0], bq3, nullptr,
                                              Qb, Kbf, Vpb, 1024, 3072);
  vtrans_k<<<dim3(16, 64), dim3(512), 0, stream>>>(Vpb, Vtb);
  attn_k<<<dim3(8, 64), dim3(512), 0, stream>>>(Qb, Kbf, Vtb, AOb);
  gemm64_k<2><<<dim3(16, 32), blk, 0, stream>>>(AOb, wt[3], sa_bo, x, x1, 1024, 1024);

  // x = x + CrossAttn(ln1(x), x_encoder) — fused KV, V plain + transpose
  ln_k<<<4096, blk, 0, stream>>>(x1, ln1_g, ln1_b, lnbuf);
  gemm64_k<0><<<dim3(16, 32), blk, 0, stream>>>(lnbuf, wt[4], ca_bq, nullptr, Qb, 1024, 1024);
  gemm_k<5><<<dim3(16, 32), blk, 0, stream>>>(xe_bf, wt[5], bkv2, nullptr,
                                              Kbf, Vpb, nullptr, 1024, 2048);
  vtrans_k<<<dim3(16, 64), dim3(512), 0, stream>>>(Vpb, Vtb);
  attn_k<<<dim3(8, 64), dim3(512), 0, stream>>>(Qb, Kbf, Vtb, AOb);
  gemm64_k<2><<<dim3(16, 32), blk, 0, stream>>>(AOb, wt[7], ca_bo, x1, x2, 1024, 1024);

  // x = x + MLP(ln2(x)) — MLP1 back on the proven 128^2 2-phase gemm_k
  ln_k<<<4096, blk, 0, stream>>>(x2, ln2_g, ln2_b, lnbuf);
  gemm_k<3><<<dim3(32, 32), blk, 0, stream>>>(lnbuf, w1t, mlp_b1, nullptr,
                                              Hb, nullptr, nullptr, 1024, 4096);
  gemm64_k<2><<<dim3(16, 32), blk, 0, stream>>>(Hb, w2t, mlp_b2, x2,
                                                (float*)d_out, 4096, 1024);

  (void)in_sizes; (void)n_in; (void)out_size; (void)ws_size;
}